// Round 1
// baseline (270.956 us; speedup 1.0000x reference)
//
#include <hip/hip_runtime.h>

#define AS1 __attribute__((address_space(1)))
#define AS3 __attribute__((address_space(3)))

typedef __bf16 bf16x8 __attribute__((ext_vector_type(8)));
typedef float f32x4 __attribute__((ext_vector_type(4)));

static constexpr int S = 4;
static constexpr int NATOMS = 32768;
static constexpr int FIN = 512;
static constexpr int H = 256;
static constexpr int BM = 64;

// ---------------- weight packing: fp32 [S][K][H] -> fragment-major bf16 hi/lo ----------------
// frag block = 64 lanes x (8 hi + 8 lo) bf16 = 1024 elems. Element (lane,j):
//   k = kt*32 + (lane>>4)*8 + j ; n = nt*16 + (lane&15)
__global__ void pack_w(const float* __restrict__ W, __bf16* __restrict__ dst, int KT) {
    int idx = blockIdx.x * 256 + threadIdx.x;
    int j = idx & 7;
    int lane = (idx >> 3) & 63;
    int rest = idx >> 9;
    int kt = rest % KT;
    int t2 = rest / KT;            // s*16 + nt
    int K = KT * 32;
    int k = kt * 32 + (lane >> 4) * 8 + j;
    int n = (t2 & 15) * 16 + (lane & 15);
    int s = t2 >> 4;
    float v = W[((size_t)s * K + k) * H + n];
    __bf16 hi = (__bf16)v;
    __bf16 lo = (__bf16)(v - (float)hi);
    size_t o = (((size_t)t2 * KT + kt) * 64 + lane) * 16 + j;
    dst[o] = hi;
    dst[o + 8] = lo;
}

__global__ void init_out(float* __restrict__ out, const float* __restrict__ shift, int n) {
    int i = blockIdx.x * 256 + threadIdx.x;
    if (i < n) out[i] = shift[0];
}

// convert 8 consecutive fp32 (16B-aligned) in LDS to bf16 hi + lo fragments
__device__ __forceinline__ void cvt8(const float* p, bf16x8& hi, bf16x8& lo) {
    f32x4 a = *(const f32x4*)p;
    f32x4 b = *(const f32x4*)(p + 4);
#pragma unroll
    for (int j = 0; j < 4; ++j) {
        __bf16 h0 = (__bf16)a[j];
        hi[j] = h0;
        lo[j] = (__bf16)(a[j] - (float)h0);
        __bf16 h1 = (__bf16)b[j];
        hi[j + 4] = h1;
        lo[j + 4] = (__bf16)(b[j] - (float)h1);
    }
}

__global__ __launch_bounds__(256, 2) void fused_mlp(
    const float* __restrict__ X, const int* __restrict__ ids,
    const __bf16* __restrict__ W1p, const __bf16* __restrict__ W2p,
    const __bf16* __restrict__ W3p,
    const float* __restrict__ b1, const float* __restrict__ b2,
    const float* __restrict__ b3,
    const float* __restrict__ W4, const float* __restrict__ b4,
    float* __restrict__ out)
{
    // h buffer: [64][256+4] fp32 (pad 4 floats -> row stride 1040B, 16B aligned,
    // bank stride 4 -> 16 lanes reading same col-block across rows = 2-way = free)
    __shared__ float hbuf[BM][H + 4];
    __shared__ float e_lds[4][BM];

    const int s = blockIdx.y;
    const int tile = blockIdx.x;
    const int tid = threadIdx.x;
    const int w = tid >> 6;
    const int lane = tid & 63;
    const int g = lane >> 4;
    const int mh = lane & 15;

    // layer-1 staging buffer aliases hbuf: [64][64+4] fp32 (272B rows, 16B aligned)
    float (*xs)[68] = reinterpret_cast<float (*)[68]>(&hbuf[0][0]);

    const float* Xb = X + (size_t)(s * NATOMS + tile * BM) * FIN;

    f32x4 acc[4][4];
#pragma unroll
    for (int i = 0; i < 4; ++i)
#pragma unroll
        for (int j = 0; j < 4; ++j)
            acc[i][j] = f32x4{0.f, 0.f, 0.f, 0.f};

    // ---------------- layer 1: [64x512] @ [512x256] ----------------
    for (int k0 = 0; k0 < FIN; k0 += 64) {
        // stage one 64-float row per instruction: uniform LDS base, per-lane global addr
#pragma unroll
        for (int i = 0; i < 16; ++i) {
            int r = w * 16 + i;
            __builtin_amdgcn_global_load_lds(
                (const AS1 unsigned int*)(Xb + (size_t)r * FIN + k0 + lane),
                (AS3 unsigned int*)(&xs[r][0]), 4, 0, 0);
        }
        __syncthreads();
#pragma unroll
        for (int ks = 0; ks < 2; ++ks) {
            bf16x8 ahi[4], alo[4];
#pragma unroll
            for (int mt = 0; mt < 4; ++mt)
                cvt8(&xs[mt * 16 + mh][ks * 32 + g * 8], ahi[mt], alo[mt]);
#pragma unroll
            for (int nt = 0; nt < 4; ++nt) {
                const __bf16* fp = W1p +
                    ((((size_t)(s * 16 + w * 4 + nt)) * 16 + (k0 >> 5) + ks) << 10) +
                    lane * 16;
                bf16x8 bhi = *(const bf16x8*)fp;
                bf16x8 blo = *(const bf16x8*)(fp + 8);
#pragma unroll
                for (int mt = 0; mt < 4; ++mt) {
                    acc[mt][nt] = __builtin_amdgcn_mfma_f32_16x16x32_bf16(ahi[mt], bhi, acc[mt][nt], 0, 0, 0);
                    acc[mt][nt] = __builtin_amdgcn_mfma_f32_16x16x32_bf16(alo[mt], bhi, acc[mt][nt], 0, 0, 0);
                    acc[mt][nt] = __builtin_amdgcn_mfma_f32_16x16x32_bf16(ahi[mt], blo, acc[mt][nt], 0, 0, 0);
                }
            }
        }
        __syncthreads();
    }

    // bias + silu -> h1 (overwrites xs region; safe after final barrier above)
    {
        float bv[4];
#pragma unroll
        for (int nt = 0; nt < 4; ++nt) bv[nt] = b1[s * H + w * 64 + nt * 16 + mh];
#pragma unroll
        for (int mt = 0; mt < 4; ++mt)
#pragma unroll
            for (int nt = 0; nt < 4; ++nt)
#pragma unroll
                for (int r = 0; r < 4; ++r) {
                    float v = acc[mt][nt][r] + bv[nt];
                    v = v / (1.f + __expf(-v));
                    hbuf[mt * 16 + g * 4 + r][w * 64 + nt * 16 + mh] = v;
                    acc[mt][nt][r] = 0.f;
                }
    }
    __syncthreads();

    // ---------------- layers 2 and 3: [64x256] @ [256x256] ----------------
    for (int l = 0; l < 2; ++l) {
        const __bf16* Wp = l ? W3p : W2p;
#pragma unroll
        for (int ks = 0; ks < 8; ++ks) {
            bf16x8 ahi[4], alo[4];
#pragma unroll
            for (int mt = 0; mt < 4; ++mt)
                cvt8(&hbuf[mt * 16 + mh][ks * 32 + g * 8], ahi[mt], alo[mt]);
#pragma unroll
            for (int nt = 0; nt < 4; ++nt) {
                const __bf16* fp = Wp +
                    ((((size_t)(s * 16 + w * 4 + nt)) * 8 + ks) << 10) + lane * 16;
                bf16x8 bhi = *(const bf16x8*)fp;
                bf16x8 blo = *(const bf16x8*)(fp + 8);
#pragma unroll
                for (int mt = 0; mt < 4; ++mt) {
                    acc[mt][nt] = __builtin_amdgcn_mfma_f32_16x16x32_bf16(ahi[mt], bhi, acc[mt][nt], 0, 0, 0);
                    acc[mt][nt] = __builtin_amdgcn_mfma_f32_16x16x32_bf16(alo[mt], bhi, acc[mt][nt], 0, 0, 0);
                    acc[mt][nt] = __builtin_amdgcn_mfma_f32_16x16x32_bf16(ahi[mt], blo, acc[mt][nt], 0, 0, 0);
                }
            }
        }
        __syncthreads();  // all reads of h done before overwrite
        if (l == 0) {
            float bv[4];
#pragma unroll
            for (int nt = 0; nt < 4; ++nt) bv[nt] = b2[s * H + w * 64 + nt * 16 + mh];
#pragma unroll
            for (int mt = 0; mt < 4; ++mt)
#pragma unroll
                for (int nt = 0; nt < 4; ++nt)
#pragma unroll
                    for (int r = 0; r < 4; ++r) {
                        float v = acc[mt][nt][r] + bv[nt];
                        v = v / (1.f + __expf(-v));
                        hbuf[mt * 16 + g * 4 + r][w * 64 + nt * 16 + mh] = v;
                        acc[mt][nt][r] = 0.f;
                    }
            __syncthreads();
        }
    }

    // ---------------- layer 3 activation + layer 4 dot + reduce ----------------
    {
        float bv[4], w4v[4];
#pragma unroll
        for (int nt = 0; nt < 4; ++nt) {
            int col = w * 64 + nt * 16 + mh;
            bv[nt] = b3[s * H + col];
            w4v[nt] = W4[s * H + col];
        }
#pragma unroll
        for (int mt = 0; mt < 4; ++mt)
#pragma unroll
            for (int r = 0; r < 4; ++r) {
                float v = 0.f;
#pragma unroll
                for (int nt = 0; nt < 4; ++nt) {
                    float h = acc[mt][nt][r] + bv[nt];
                    h = h / (1.f + __expf(-h));
                    v += h * w4v[nt];
                }
                // reduce across the 16 lanes (lane&15) that hold this row's columns
                v += __shfl_xor(v, 1);
                v += __shfl_xor(v, 2);
                v += __shfl_xor(v, 4);
                v += __shfl_xor(v, 8);
                if (mh == r) e_lds[w][mt * 16 + g * 4 + r] = v;
            }
    }
    __syncthreads();
    if (tid < BM) {
        float e = e_lds[0][tid] + e_lds[1][tid] + e_lds[2][tid] + e_lds[3][tid] + b4[s];
        int id = ids[s * NATOMS + tile * BM + tid];
        atomicAdd(&out[id], e);
    }
}

extern "C" void kernel_launch(void* const* d_in, const int* in_sizes, int n_in,
                              void* d_out, int out_size, void* d_ws, size_t ws_size,
                              hipStream_t stream) {
    const float* X   = (const float*)d_in[0];
    const int*   ids = (const int*)d_in[1];
    const float* W1  = (const float*)d_in[2];
    const float* b1  = (const float*)d_in[3];
    const float* W2  = (const float*)d_in[4];
    const float* b2  = (const float*)d_in[5];
    const float* W3  = (const float*)d_in[6];
    const float* b3  = (const float*)d_in[7];
    const float* W4  = (const float*)d_in[8];
    const float* b4  = (const float*)d_in[9];
    const float* shift = (const float*)d_in[10];

    // packed weights in workspace: W1p 2MB, W2p 1MB, W3p 1MB (bf16 hi/lo)
    __bf16* W1p = (__bf16*)d_ws;
    __bf16* W2p = W1p + (size_t)S * 16 * 16 * 1024;
    __bf16* W3p = W2p + (size_t)S * 16 * 8 * 1024;

    pack_w<<<128 * 16, 256, 0, stream>>>(W1, W1p, 16);
    pack_w<<<128 * 8, 256, 0, stream>>>(W2, W2p, 8);
    pack_w<<<128 * 8, 256, 0, stream>>>(W3, W3p, 8);

    init_out<<<(out_size + 255) / 256, 256, 0, stream>>>((float*)d_out, shift, out_size);

    dim3 grid(NATOMS / BM, S);
    fused_mlp<<<grid, 256, 0, stream>>>(X, ids, W1p, W2p, W3p, b1, b2, b3, W4, b4,
                                        (float*)d_out);
}

// Round 2
// 225.849 us; speedup vs baseline: 1.1997x; 1.1997x over previous
//
#include <hip/hip_runtime.h>

typedef _Float16 f16x8 __attribute__((ext_vector_type(8)));
typedef _Float16 f16x4 __attribute__((ext_vector_type(4)));
typedef float f32x4 __attribute__((ext_vector_type(4)));

static constexpr int S = 4;
static constexpr int NATOMS = 32768;
static constexpr int FIN = 512;
static constexpr int H = 256;
static constexpr int BM = 64;
static constexpr int XSTR = 136;  // 128-col chunk + 8 fp16 pad (stride 272B: 2-way banks only)
static constexpr int HSTR = 264;  // 256 cols + 8 pad (stride 528B)

// ---------------- weight packing: fp32 [S][K][H] -> fragment-major fp16 hi/lo ----------------
// frag block = 64 lanes x (8 hi + 8 lo) fp16. Element (lane,j):
//   k = kt*32 + (lane>>4)*8 + j ; n = nt*16 + (lane&15)
__global__ void pack_w(const float* __restrict__ W, _Float16* __restrict__ dst, int KT) {
    int idx = blockIdx.x * 256 + threadIdx.x;
    int j = idx & 7;
    int lane = (idx >> 3) & 63;
    int rest = idx >> 9;
    int kt = rest % KT;
    int t2 = rest / KT;            // s*16 + nt
    int K = KT * 32;
    int k = kt * 32 + (lane >> 4) * 8 + j;
    int n = (t2 & 15) * 16 + (lane & 15);
    int s = t2 >> 4;
    float v = W[((size_t)s * K + k) * H + n];
    _Float16 hi = (_Float16)v;
    _Float16 lo = (_Float16)(v - (float)hi);
    size_t o = (((size_t)t2 * KT + kt) * 64 + lane) * 16 + j;
    dst[o] = hi;
    dst[o + 8] = lo;
}

__global__ void init_out(float* __restrict__ out, const float* __restrict__ shift, int n) {
    int i = blockIdx.x * 256 + threadIdx.x;
    if (i < n) out[i] = shift[0];
}

__global__ __launch_bounds__(256, 3) void fused_mlp(
    const float* __restrict__ X, const int* __restrict__ ids,
    const _Float16* __restrict__ W1p, const _Float16* __restrict__ W2p,
    const _Float16* __restrict__ W3p,
    const float* __restrict__ b1, const float* __restrict__ b2,
    const float* __restrict__ b3,
    const float* __restrict__ W4, const float* __restrict__ b4,
    float* __restrict__ out)
{
    // union region: X chunk double-buffer (2 x 64 x 136 fp16 = 34816B) aliased by
    // h plane (64 x 264 fp16 = 33792B). h written only after all layer-1 reads done.
    __shared__ _Float16 smem[2 * BM * XSTR];
    __shared__ float e_lds[4][BM];

    const int s = blockIdx.y;
    const int tile = blockIdx.x;
    const int tid = threadIdx.x;
    const int w = tid >> 6;
    const int lane = tid & 63;
    const int g = lane >> 4;
    const int mh = lane & 15;
    const int q = tid & 31;        // staging col-quad
    const int rr = tid >> 5;       // staging row offset

    const float* Xb = X + (size_t)(s * NATOMS + tile * BM) * FIN;
    _Float16* hb = smem;

    f32x4 acc[4][4];
#pragma unroll
    for (int i = 0; i < 4; ++i)
#pragma unroll
        for (int j = 0; j < 4; ++j)
            acc[i][j] = f32x4{0.f, 0.f, 0.f, 0.f};

    // ---- layer-1 pipeline helpers (c = chunk 0..3, 128 cols each) ----
    auto issue = [&](f32x4* ld, int c) {
#pragma unroll
        for (int i = 0; i < 8; ++i)
            ld[i] = *(const f32x4*)(Xb + (size_t)(i * 8 + rr) * FIN + c * 128 + q * 4);
    };
    auto stage = [&](const f32x4* ld, int c) {
        _Float16* xb = smem + (c & 1) * (BM * XSTR);
#pragma unroll
        for (int i = 0; i < 8; ++i) {
            f16x4 h4;
            h4[0] = (_Float16)ld[i][0];
            h4[1] = (_Float16)ld[i][1];
            h4[2] = (_Float16)ld[i][2];
            h4[3] = (_Float16)ld[i][3];
            *(f16x4*)(xb + (i * 8 + rr) * XSTR + q * 4) = h4;
        }
    };
    auto l1mfma = [&](int c) {
        const _Float16* xb = smem + (c & 1) * (BM * XSTR);
#pragma unroll
        for (int ks = 0; ks < 4; ++ks) {
            f16x8 a[4];
#pragma unroll
            for (int mt = 0; mt < 4; ++mt)
                a[mt] = *(const f16x8*)(xb + (mt * 16 + mh) * XSTR + ks * 32 + g * 8);
#pragma unroll
            for (int nt = 0; nt < 4; ++nt) {
                const _Float16* fp = W1p +
                    ((((size_t)(s * 16 + w * 4 + nt)) * 16 + c * 4 + ks) << 10) + lane * 16;
                f16x8 bhi = *(const f16x8*)fp;
                f16x8 blo = *(const f16x8*)(fp + 8);
#pragma unroll
                for (int mt = 0; mt < 4; ++mt) {
                    acc[mt][nt] = __builtin_amdgcn_mfma_f32_16x16x32_f16(a[mt], bhi, acc[mt][nt], 0, 0, 0);
                    acc[mt][nt] = __builtin_amdgcn_mfma_f32_16x16x32_f16(a[mt], blo, acc[mt][nt], 0, 0, 0);
                }
            }
        }
    };

    // ---------------- layer 1: [64x512] @ [512x256], 2-deep pipelined ----------------
    f32x4 ldA[8], ldB[8];
    issue(ldA, 0);
    stage(ldA, 0); __syncthreads(); issue(ldB, 1); l1mfma(0);
    stage(ldB, 1); __syncthreads(); issue(ldA, 2); l1mfma(1);
    stage(ldA, 2); __syncthreads(); issue(ldB, 3); l1mfma(2);
    stage(ldB, 3); __syncthreads();                l1mfma(3);
    __syncthreads();  // all layer-1 LDS reads done before h overwrites the union

    // bias + silu -> h1 (fp16 plane)
    {
        float bv[4];
#pragma unroll
        for (int nt = 0; nt < 4; ++nt) bv[nt] = b1[s * H + w * 64 + nt * 16 + mh];
#pragma unroll
        for (int mt = 0; mt < 4; ++mt)
#pragma unroll
            for (int nt = 0; nt < 4; ++nt)
#pragma unroll
                for (int r = 0; r < 4; ++r) {
                    float v = acc[mt][nt][r] + bv[nt];
                    v = v / (1.f + __expf(-v));
                    hb[(mt * 16 + g * 4 + r) * HSTR + w * 64 + nt * 16 + mh] = (_Float16)v;
                    acc[mt][nt][r] = 0.f;
                }
    }
    __syncthreads();

    // ---------------- layers 2 and 3: [64x256] @ [256x256] ----------------
    for (int l = 0; l < 2; ++l) {
        const _Float16* Wp = l ? W3p : W2p;
#pragma unroll
        for (int ks = 0; ks < 8; ++ks) {
            f16x8 a[4];
#pragma unroll
            for (int mt = 0; mt < 4; ++mt)
                a[mt] = *(const f16x8*)(hb + (mt * 16 + mh) * HSTR + ks * 32 + g * 8);
#pragma unroll
            for (int nt = 0; nt < 4; ++nt) {
                const _Float16* fp = Wp +
                    ((((size_t)(s * 16 + w * 4 + nt)) * 8 + ks) << 10) + lane * 16;
                f16x8 bhi = *(const f16x8*)fp;
                f16x8 blo = *(const f16x8*)(fp + 8);
#pragma unroll
                for (int mt = 0; mt < 4; ++mt) {
                    acc[mt][nt] = __builtin_amdgcn_mfma_f32_16x16x32_f16(a[mt], bhi, acc[mt][nt], 0, 0, 0);
                    acc[mt][nt] = __builtin_amdgcn_mfma_f32_16x16x32_f16(a[mt], blo, acc[mt][nt], 0, 0, 0);
                }
            }
        }
        __syncthreads();  // all reads of h done before overwrite
        if (l == 0) {
            float bv[4];
#pragma unroll
            for (int nt = 0; nt < 4; ++nt) bv[nt] = b2[s * H + w * 64 + nt * 16 + mh];
#pragma unroll
            for (int mt = 0; mt < 4; ++mt)
#pragma unroll
                for (int nt = 0; nt < 4; ++nt)
#pragma unroll
                    for (int r = 0; r < 4; ++r) {
                        float v = acc[mt][nt][r] + bv[nt];
                        v = v / (1.f + __expf(-v));
                        hb[(mt * 16 + g * 4 + r) * HSTR + w * 64 + nt * 16 + mh] = (_Float16)v;
                        acc[mt][nt][r] = 0.f;
                    }
            __syncthreads();
        }
    }

    // ---------------- layer 3 activation + layer 4 dot + reduce ----------------
    {
        float bv[4], w4v[4];
#pragma unroll
        for (int nt = 0; nt < 4; ++nt) {
            int col = w * 64 + nt * 16 + mh;
            bv[nt] = b3[s * H + col];
            w4v[nt] = W4[s * H + col];
        }
#pragma unroll
        for (int mt = 0; mt < 4; ++mt)
#pragma unroll
            for (int r = 0; r < 4; ++r) {
                float v = 0.f;
#pragma unroll
                for (int nt = 0; nt < 4; ++nt) {
                    float h = acc[mt][nt][r] + bv[nt];
                    h = h / (1.f + __expf(-h));
                    v += h * w4v[nt];
                }
                v += __shfl_xor(v, 1);
                v += __shfl_xor(v, 2);
                v += __shfl_xor(v, 4);
                v += __shfl_xor(v, 8);
                if (mh == r) e_lds[w][mt * 16 + g * 4 + r] = v;
            }
    }
    __syncthreads();
    if (tid < BM) {
        float e = e_lds[0][tid] + e_lds[1][tid] + e_lds[2][tid] + e_lds[3][tid] + b4[s];
        int id = ids[s * NATOMS + tile * BM + tid];
        atomicAdd(&out[id], e);
    }
}

extern "C" void kernel_launch(void* const* d_in, const int* in_sizes, int n_in,
                              void* d_out, int out_size, void* d_ws, size_t ws_size,
                              hipStream_t stream) {
    const float* X   = (const float*)d_in[0];
    const int*   ids = (const int*)d_in[1];
    const float* W1  = (const float*)d_in[2];
    const float* b1  = (const float*)d_in[3];
    const float* W2  = (const float*)d_in[4];
    const float* b2  = (const float*)d_in[5];
    const float* W3  = (const float*)d_in[6];
    const float* b3  = (const float*)d_in[7];
    const float* W4  = (const float*)d_in[8];
    const float* b4  = (const float*)d_in[9];
    const float* shift = (const float*)d_in[10];

    // packed fp16 hi/lo weights in workspace: W1p 2MB, W2p 1MB, W3p 1MB
    _Float16* W1p = (_Float16*)d_ws;
    _Float16* W2p = W1p + (size_t)S * 16 * 16 * 1024;
    _Float16* W3p = W2p + (size_t)S * 16 * 8 * 1024;

    pack_w<<<128 * 16, 256, 0, stream>>>(W1, W1p, 16);
    pack_w<<<128 * 8, 256, 0, stream>>>(W2, W2p, 8);
    pack_w<<<128 * 8, 256, 0, stream>>>(W3, W3p, 8);

    init_out<<<(out_size + 255) / 256, 256, 0, stream>>>((float*)d_out, shift, out_size);

    dim3 grid(NATOMS / BM, S);
    fused_mlp<<<grid, 256, 0, stream>>>(X, ids, W1p, W2p, W3p, b1, b2, b3, W4, b4,
                                        (float*)d_out);
}

// Round 3
// 218.472 us; speedup vs baseline: 1.2402x; 1.0338x over previous
//
#include <hip/hip_runtime.h>

typedef _Float16 f16x8 __attribute__((ext_vector_type(8)));
typedef _Float16 f16x4 __attribute__((ext_vector_type(4)));
typedef float f32x4 __attribute__((ext_vector_type(4)));

static constexpr int S = 4;
static constexpr int NATOMS = 32768;
static constexpr int FIN = 512;
static constexpr int H = 256;
static constexpr int BM = 128;   // atoms per block
static constexpr int XSTR = 72;  // 64-col X chunk + 8 fp16 pad (144B rows: 2-way banks, free)
static constexpr int HSTR = 264; // 256 cols + 8 pad (528B rows: 2-way banks)

// ---- weight packing: fp32 [S][K][H] -> fragment-major fp16 (1-term) ----
// frag = 64 lanes x 8 fp16. Element (lane,j): k = kt*32+(lane>>4)*8+j ; n = ntile*16+(lane&15)
__global__ void pack_w(const float* __restrict__ W, _Float16* __restrict__ dst, int KT) {
    int idx = blockIdx.x * 256 + threadIdx.x;
    int j = idx & 7;
    int lane = (idx >> 3) & 63;
    int rest = idx >> 9;
    int kt = rest % KT;
    int t2 = rest / KT;            // s*16 + ntile
    int K = KT * 32;
    int k = kt * 32 + (lane >> 4) * 8 + j;
    int n = (t2 & 15) * 16 + (lane & 15);
    int s = t2 >> 4;
    dst[(((size_t)t2 * KT + kt) * 64 + lane) * 8 + j] = (_Float16)W[((size_t)s * K + k) * H + n];
}

__global__ void init_out(float* __restrict__ out, const float* __restrict__ shift, int n) {
    int i = blockIdx.x * 256 + threadIdx.x;
    if (i < n) out[i] = shift[0];
}

__global__ __launch_bounds__(512, 4) void fused_mlp(
    const float* __restrict__ X, const int* __restrict__ ids,
    const _Float16* __restrict__ W1p, const _Float16* __restrict__ W2p,
    const _Float16* __restrict__ W3p,
    const float* __restrict__ b1, const float* __restrict__ b2,
    const float* __restrict__ b3,
    const float* __restrict__ W4, const float* __restrict__ b4,
    float* __restrict__ out)
{
    // union: h plane 128x264 fp16 (67584B) aliases the X chunk double-buffer
    // (2 x 128 x 72 fp16 = 36864B). h written only after all layer-1 reads done.
    __shared__ _Float16 smem[BM * HSTR];
    __shared__ float e_lds[4][BM];

    const int s = blockIdx.y;
    const int tile = blockIdx.x;
    const int tid = threadIdx.x;
    const int w = tid >> 6;
    const int lane = tid & 63;
    const int wm = w >> 2;         // 0..1: row-half of the 128-atom tile
    const int wn = w & 3;          // 0..3: 64-col slice of H
    const int g = lane >> 4;
    const int mh = lane & 15;
    const int q = tid & 15;        // staging col-quad (16 quads = 64 cols)
    const int rr = (tid >> 4) & 31;

    const float* Xb = X + (size_t)(s * NATOMS + tile * BM) * FIN;
    _Float16* hb = smem;

    f32x4 acc[4][4];
#pragma unroll
    for (int i = 0; i < 4; ++i)
#pragma unroll
        for (int j = 0; j < 4; ++j)
            acc[i][j] = f32x4{0.f, 0.f, 0.f, 0.f};

    // ---- layer-1 helpers (c = chunk 0..7, 64 K-cols each) ----
    auto issue = [&](f32x4* ld, int c) {
#pragma unroll
        for (int i = 0; i < 4; ++i)
            ld[i] = *(const f32x4*)(Xb + (size_t)(rr + i * 32) * FIN + c * 64 + q * 4);
    };
    auto stage = [&](const f32x4* ld, int c) {
        _Float16* xb = smem + (c & 1) * (BM * XSTR);
#pragma unroll
        for (int i = 0; i < 4; ++i) {
            f16x4 h4;
            h4[0] = (_Float16)ld[i][0];
            h4[1] = (_Float16)ld[i][1];
            h4[2] = (_Float16)ld[i][2];
            h4[3] = (_Float16)ld[i][3];
            *(f16x4*)(xb + (rr + i * 32) * XSTR + q * 4) = h4;
        }
    };
    auto l1mfma = [&](int c) {
        const _Float16* xb = smem + (c & 1) * (BM * XSTR);
#pragma unroll
        for (int ks = 0; ks < 2; ++ks) {
            f16x8 a[4];
#pragma unroll
            for (int mt = 0; mt < 4; ++mt)
                a[mt] = *(const f16x8*)(xb + (wm * 64 + mt * 16 + mh) * XSTR + ks * 32 + g * 8);
#pragma unroll
            for (int nt = 0; nt < 4; ++nt) {
                const _Float16* fp = W1p +
                    ((((size_t)(s * 16 + wn * 4 + nt)) * 16 + c * 2 + ks) << 9) + lane * 8;
                f16x8 b = *(const f16x8*)fp;
#pragma unroll
                for (int mt = 0; mt < 4; ++mt)
                    acc[mt][nt] = __builtin_amdgcn_mfma_f32_16x16x32_f16(a[mt], b, acc[mt][nt], 0, 0, 0);
            }
        }
    };

    // ---------------- layer 1: [128x512] @ [512x256], 2-buffer pipeline ----------------
    f32x4 ld[2][4];
    issue(ld[0], 0);
#pragma unroll
    for (int c = 0; c < 8; ++c) {
        stage(ld[c & 1], c);
        __syncthreads();
        if (c < 7) issue(ld[(c + 1) & 1], c + 1);
        l1mfma(c);
    }
    __syncthreads();  // all layer-1 LDS reads done before h overwrites the union

    // bias + silu -> h1 (fp16 plane)
    {
        float bv[4];
#pragma unroll
        for (int nt = 0; nt < 4; ++nt) bv[nt] = b1[s * H + wn * 64 + nt * 16 + mh];
#pragma unroll
        for (int mt = 0; mt < 4; ++mt)
#pragma unroll
            for (int nt = 0; nt < 4; ++nt)
#pragma unroll
                for (int r = 0; r < 4; ++r) {
                    float v = acc[mt][nt][r] + bv[nt];
                    v = v / (1.f + __expf(-v));
                    hb[(wm * 64 + mt * 16 + g * 4 + r) * HSTR + wn * 64 + nt * 16 + mh] = (_Float16)v;
                    acc[mt][nt][r] = 0.f;
                }
    }
    __syncthreads();

    // ---------------- layers 2 and 3: [128x256] @ [256x256] ----------------
    for (int l = 0; l < 2; ++l) {
        const _Float16* Wp = l ? W3p : W2p;
#pragma unroll
        for (int ks = 0; ks < 8; ++ks) {
            f16x8 a[4];
#pragma unroll
            for (int mt = 0; mt < 4; ++mt)
                a[mt] = *(const f16x8*)(hb + (wm * 64 + mt * 16 + mh) * HSTR + ks * 32 + g * 8);
#pragma unroll
            for (int nt = 0; nt < 4; ++nt) {
                const _Float16* fp = Wp +
                    ((((size_t)(s * 16 + wn * 4 + nt)) * 8 + ks) << 9) + lane * 8;
                f16x8 b = *(const f16x8*)fp;
#pragma unroll
                for (int mt = 0; mt < 4; ++mt)
                    acc[mt][nt] = __builtin_amdgcn_mfma_f32_16x16x32_f16(a[mt], b, acc[mt][nt], 0, 0, 0);
            }
        }
        __syncthreads();  // all reads of h done before overwrite
        if (l == 0) {
            float bv[4];
#pragma unroll
            for (int nt = 0; nt < 4; ++nt) bv[nt] = b2[s * H + wn * 64 + nt * 16 + mh];
#pragma unroll
            for (int mt = 0; mt < 4; ++mt)
#pragma unroll
                for (int nt = 0; nt < 4; ++nt)
#pragma unroll
                    for (int r = 0; r < 4; ++r) {
                        float v = acc[mt][nt][r] + bv[nt];
                        v = v / (1.f + __expf(-v));
                        hb[(wm * 64 + mt * 16 + g * 4 + r) * HSTR + wn * 64 + nt * 16 + mh] = (_Float16)v;
                        acc[mt][nt][r] = 0.f;
                    }
            __syncthreads();
        }
    }

    // ---------------- layer 3 activation + layer 4 dot + reduce ----------------
    {
        float bv[4], w4v[4];
#pragma unroll
        for (int nt = 0; nt < 4; ++nt) {
            int col = wn * 64 + nt * 16 + mh;
            bv[nt] = b3[s * H + col];
            w4v[nt] = W4[s * H + col];
        }
#pragma unroll
        for (int mt = 0; mt < 4; ++mt)
#pragma unroll
            for (int r = 0; r < 4; ++r) {
                float v = 0.f;
#pragma unroll
                for (int nt = 0; nt < 4; ++nt) {
                    float h = acc[mt][nt][r] + bv[nt];
                    h = h / (1.f + __expf(-h));
                    v += h * w4v[nt];
                }
                v += __shfl_xor(v, 1);
                v += __shfl_xor(v, 2);
                v += __shfl_xor(v, 4);
                v += __shfl_xor(v, 8);
                if (mh == r) e_lds[wn][wm * 64 + mt * 16 + g * 4 + r] = v;
            }
    }
    __syncthreads();
    if (tid < BM) {
        float e = e_lds[0][tid] + e_lds[1][tid] + e_lds[2][tid] + e_lds[3][tid] + b4[s];
        int id = ids[s * NATOMS + tile * BM + tid];
        atomicAdd(&out[id], e);
    }
}

extern "C" void kernel_launch(void* const* d_in, const int* in_sizes, int n_in,
                              void* d_out, int out_size, void* d_ws, size_t ws_size,
                              hipStream_t stream) {
    const float* X   = (const float*)d_in[0];
    const int*   ids = (const int*)d_in[1];
    const float* W1  = (const float*)d_in[2];
    const float* b1  = (const float*)d_in[3];
    const float* W2  = (const float*)d_in[4];
    const float* b2  = (const float*)d_in[5];
    const float* W3  = (const float*)d_in[6];
    const float* b3  = (const float*)d_in[7];
    const float* W4  = (const float*)d_in[8];
    const float* b4  = (const float*)d_in[9];
    const float* shift = (const float*)d_in[10];

    // packed fp16 weights (1-term): W1p 1MB, W2p 512KB, W3p 512KB
    _Float16* W1p = (_Float16*)d_ws;
    _Float16* W2p = W1p + (size_t)S * 16 * 16 * 512;
    _Float16* W3p = W2p + (size_t)S * 16 * 8 * 512;

    pack_w<<<2048, 256, 0, stream>>>(W1, W1p, 16);
    pack_w<<<1024, 256, 0, stream>>>(W2, W2p, 8);
    pack_w<<<1024, 256, 0, stream>>>(W3, W3p, 8);

    init_out<<<(out_size + 255) / 256, 256, 0, stream>>>((float*)d_out, shift, out_size);

    dim3 grid(NATOMS / BM, S);
    fused_mlp<<<grid, 512, 0, stream>>>(X, ids, W1p, W2p, W3p, b1, b2, b3, W4, b4,
                                        (float*)d_out);
}

// Round 4
// 203.142 us; speedup vs baseline: 1.3338x; 1.0755x over previous
//
#include <hip/hip_runtime.h>

#define AS1 __attribute__((address_space(1)))
#define AS3 __attribute__((address_space(3)))

typedef _Float16 f16x8 __attribute__((ext_vector_type(8)));
typedef float f32x4 __attribute__((ext_vector_type(4)));

static constexpr int S = 4;
static constexpr int NATOMS = 32768;
static constexpr int FIN = 512;
static constexpr int H = 256;
static constexpr int BM = 64;    // atoms per block
static constexpr int HSTR = 264; // h plane: 256 cols + 8 pad (528B rows -> 2-way banks, free)

// ---- weight packing: fp32 [S][K][H] -> fragment-major fp16 (1-term) ----
// frag = 64 lanes x 8 fp16. Element (lane,j): k = kt*32+(lane>>4)*8+j ; n = ntile*16+(lane&15)
__global__ void pack_w(const float* __restrict__ W, _Float16* __restrict__ dst, int KT) {
    int idx = blockIdx.x * 256 + threadIdx.x;
    int j = idx & 7;
    int lane = (idx >> 3) & 63;
    int rest = idx >> 9;
    int kt = rest % KT;
    int t2 = rest / KT;            // s*16 + ntile
    int K = KT * 32;
    int k = kt * 32 + (lane >> 4) * 8 + j;
    int n = (t2 & 15) * 16 + (lane & 15);
    int s = t2 >> 4;
    dst[(((size_t)t2 * KT + kt) * 64 + lane) * 8 + j] = (_Float16)W[((size_t)s * K + k) * H + n];
}

__global__ void init_out(float* __restrict__ out, const float* __restrict__ shift, int n) {
    int i = blockIdx.x * 256 + threadIdx.x;
    if (i < n) out[i] = shift[0];
}

__global__ __launch_bounds__(256, 4) void fused_mlp(
    const float* __restrict__ X, const int* __restrict__ ids,
    const _Float16* __restrict__ W1p, const _Float16* __restrict__ W2p,
    const _Float16* __restrict__ W3p,
    const float* __restrict__ b1, const float* __restrict__ b2,
    const float* __restrict__ b3,
    const float* __restrict__ W4, const float* __restrict__ b4,
    float* __restrict__ out)
{
    // union: X fp32 double-buffer [2][64][64] (32768B) aliased by h fp16 [64][264]
    // (33792B). h written only after all layer-1 LDS reads are done.
    __shared__ float smem[BM * HSTR / 2];   // 8448 floats = 33792B
    __shared__ float e_lds[4][BM];

    const int s = blockIdx.y;
    const int tile = blockIdx.x;
    const int tid = threadIdx.x;
    const int w = tid >> 6;        // 0..3: 64-col slice of H (N-split)
    const int lane = tid & 63;
    const int g = lane >> 4;
    const int mh = lane & 15;

    const float* Xb = X + (size_t)(s * NATOMS + tile * BM) * FIN;
    _Float16* hb = (_Float16*)smem;

    f32x4 acc[4][4];
#pragma unroll
    for (int i = 0; i < 4; ++i)
#pragma unroll
        for (int j = 0; j < 4; ++j)
            acc[i][j] = f32x4{0.f, 0.f, 0.f, 0.f};

    // ---- layer-1 staging: global_load_lds width-16, source-swizzled ----
    // LDS layout (per chunk buf): [64 rows][16 granules of 16B]; LDS[row][gr] holds
    // global granule gr^(row&7) -> fragment reads are bank-spread (2-way only).
    auto issue = [&](int c) {
        float* xb = smem + (c & 1) * (BM * 64);
        const float* src = Xb + c * 64;
#pragma unroll
        for (int i = 0; i < 4; ++i) {
            int rb = w * 16 + i * 4;               // 4 rows per issue
            int row = rb + (lane >> 4);
            int gg = (lane & 15) ^ (row & 7);
            __builtin_amdgcn_global_load_lds(
                (const AS1 unsigned int*)(src + (size_t)row * FIN + gg * 4),
                (AS3 unsigned int*)(xb + rb * 64), 16, 0, 0);
        }
    };
    auto l1mfma = [&](int c) {
        const float* xb = smem + (c & 1) * (BM * 64);
#pragma unroll
        for (int ks = 0; ks < 2; ++ks) {
            f16x8 a[4];
#pragma unroll
            for (int mt = 0; mt < 4; ++mt) {
                int m = mt * 16 + mh;
                int G0 = ks * 8 + g * 2;
                f32x4 u = *(const f32x4*)(xb + m * 64 + ((G0 ^ (m & 7)) << 2));
                f32x4 v = *(const f32x4*)(xb + m * 64 + (((G0 + 1) ^ (m & 7)) << 2));
                f16x8 a8;
#pragma unroll
                for (int j = 0; j < 4; ++j) {
                    a8[j] = (_Float16)u[j];
                    a8[j + 4] = (_Float16)v[j];
                }
                a[mt] = a8;
            }
#pragma unroll
            for (int nt = 0; nt < 4; ++nt) {
                const _Float16* fp = W1p +
                    ((((size_t)(s * 16 + w * 4 + nt)) * 16 + c * 2 + ks) << 9) + lane * 8;
                f16x8 b = *(const f16x8*)fp;
#pragma unroll
                for (int mt = 0; mt < 4; ++mt)
                    acc[mt][nt] = __builtin_amdgcn_mfma_f32_16x16x32_f16(a[mt], b, acc[mt][nt], 0, 0, 0);
            }
        }
    };

    // ---------------- layer 1: [64x512] @ [512x256], double-buffered ----------------
    issue(0);
#pragma unroll
    for (int c = 0; c < 8; ++c) {
        __syncthreads();           // implicit vmcnt(0): buf[c&1] staged, prior reads done
        if (c < 7) issue(c + 1);   // next chunk in flight under this chunk's MFMA
        l1mfma(c);
    }
    __syncthreads();  // all layer-1 LDS reads done before h overwrites the union

    // bias + silu -> h1 (fp16 plane)
    {
        float bv[4];
#pragma unroll
        for (int nt = 0; nt < 4; ++nt) bv[nt] = b1[s * H + w * 64 + nt * 16 + mh];
#pragma unroll
        for (int mt = 0; mt < 4; ++mt)
#pragma unroll
            for (int nt = 0; nt < 4; ++nt)
#pragma unroll
                for (int r = 0; r < 4; ++r) {
                    float v = acc[mt][nt][r] + bv[nt];
                    v = v / (1.f + __expf(-v));
                    hb[(mt * 16 + g * 4 + r) * HSTR + w * 64 + nt * 16 + mh] = (_Float16)v;
                    acc[mt][nt][r] = 0.f;
                }
    }
    __syncthreads();

    // ---------------- layers 2 and 3: [64x256] @ [256x256] ----------------
    for (int l = 0; l < 2; ++l) {
        const _Float16* Wp = l ? W3p : W2p;
#pragma unroll
        for (int ks = 0; ks < 8; ++ks) {
            f16x8 a[4];
#pragma unroll
            for (int mt = 0; mt < 4; ++mt)
                a[mt] = *(const f16x8*)(hb + (mt * 16 + mh) * HSTR + ks * 32 + g * 8);
#pragma unroll
            for (int nt = 0; nt < 4; ++nt) {
                const _Float16* fp = Wp +
                    ((((size_t)(s * 16 + w * 4 + nt)) * 8 + ks) << 9) + lane * 8;
                f16x8 b = *(const f16x8*)fp;
#pragma unroll
                for (int mt = 0; mt < 4; ++mt)
                    acc[mt][nt] = __builtin_amdgcn_mfma_f32_16x16x32_f16(a[mt], b, acc[mt][nt], 0, 0, 0);
            }
        }
        __syncthreads();  // all reads of h done before overwrite
        if (l == 0) {
            float bv[4];
#pragma unroll
            for (int nt = 0; nt < 4; ++nt) bv[nt] = b2[s * H + w * 64 + nt * 16 + mh];
#pragma unroll
            for (int mt = 0; mt < 4; ++mt)
#pragma unroll
                for (int nt = 0; nt < 4; ++nt)
#pragma unroll
                    for (int r = 0; r < 4; ++r) {
                        float v = acc[mt][nt][r] + bv[nt];
                        v = v / (1.f + __expf(-v));
                        hb[(mt * 16 + g * 4 + r) * HSTR + w * 64 + nt * 16 + mh] = (_Float16)v;
                        acc[mt][nt][r] = 0.f;
                    }
            __syncthreads();
        }
    }

    // ---------------- layer 3 activation + layer 4 dot + reduce ----------------
    {
        float bv[4], w4v[4];
#pragma unroll
        for (int nt = 0; nt < 4; ++nt) {
            int col = w * 64 + nt * 16 + mh;
            bv[nt] = b3[s * H + col];
            w4v[nt] = W4[s * H + col];
        }
#pragma unroll
        for (int mt = 0; mt < 4; ++mt)
#pragma unroll
            for (int r = 0; r < 4; ++r) {
                float v = 0.f;
#pragma unroll
                for (int nt = 0; nt < 4; ++nt) {
                    float h = acc[mt][nt][r] + bv[nt];
                    h = h / (1.f + __expf(-h));
                    v += h * w4v[nt];
                }
                v += __shfl_xor(v, 1);
                v += __shfl_xor(v, 2);
                v += __shfl_xor(v, 4);
                v += __shfl_xor(v, 8);
                if (mh == r) e_lds[w][mt * 16 + g * 4 + r] = v;
            }
    }
    __syncthreads();
    if (tid < BM) {
        float e = e_lds[0][tid] + e_lds[1][tid] + e_lds[2][tid] + e_lds[3][tid] + b4[s];
        int id = ids[s * NATOMS + tile * BM + tid];
        atomicAdd(&out[id], e);
    }
}

extern "C" void kernel_launch(void* const* d_in, const int* in_sizes, int n_in,
                              void* d_out, int out_size, void* d_ws, size_t ws_size,
                              hipStream_t stream) {
    const float* X   = (const float*)d_in[0];
    const int*   ids = (const int*)d_in[1];
    const float* W1  = (const float*)d_in[2];
    const float* b1  = (const float*)d_in[3];
    const float* W2  = (const float*)d_in[4];
    const float* b2  = (const float*)d_in[5];
    const float* W3  = (const float*)d_in[6];
    const float* b3  = (const float*)d_in[7];
    const float* W4  = (const float*)d_in[8];
    const float* b4  = (const float*)d_in[9];
    const float* shift = (const float*)d_in[10];

    // packed fp16 weights (1-term): W1p 1MB, W2p 512KB, W3p 512KB
    _Float16* W1p = (_Float16*)d_ws;
    _Float16* W2p = W1p + (size_t)S * 16 * 16 * 512;
    _Float16* W3p = W2p + (size_t)S * 16 * 8 * 512;

    pack_w<<<2048, 256, 0, stream>>>(W1, W1p, 16);
    pack_w<<<1024, 256, 0, stream>>>(W2, W2p, 8);
    pack_w<<<1024, 256, 0, stream>>>(W3, W3p, 8);

    init_out<<<(out_size + 255) / 256, 256, 0, stream>>>((float*)d_out, shift, out_size);

    dim3 grid(NATOMS / BM, S);
    fused_mlp<<<grid, 256, 0, stream>>>(X, ids, W1p, W2p, W3p, b1, b2, b3, W4, b4,
                                        (float*)d_out);
}